// Round 6
// baseline (8112.775 us; speedup 1.0000x reference)
//
#include <hip/hip_runtime.h>
#include <cmath>

// ---- problem constants ----
#define NB 16
#define CC 32          // channels per dictionary (A and B each)
#define HH 256
#define WW 256
#define DD 250         // 256 - 7 + 1
#define ALPHA 2.0f     // 1 + 1/RHO
#define INVL 0.1f      // 1/L
#define THR 0.01f      // LAM/L

#define IMG_SZ (HH*WW)                       // 65536
#define IMG_TOT (NB*IMG_SZ)                  // 1,048,576
#define FLD_SZ (DD*DD)                       // 62,500
#define FLD_TOT ((size_t)NB*CC*FLD_SZ)       // 32,000,000

#define LRS 260                              // lres row stride (bank-padded)

// force a block-uniform float into an SGPR (weights -> s-operand of v_fma)
__device__ __forceinline__ float rfl(float x) {
    return __int_as_float(__builtin_amdgcn_readfirstlane(__float_as_int(x)));
}

__device__ __forceinline__ float sthr(float v) {
    float a = fabsf(v) - THR; a = a > 0.f ? a : 0.f;
    return (v > 0.f) ? a : ((v < 0.f) ? -a : 0.f);
}

// ---------------------------------------------------------------------------
// k_update v6: ONE channel per block. grid = (64, 16, 16).
// Phase 1: stage res tile, computing res ON THE FLY from the 5 small images:
//          res = y - ALPHA*((1+cm)Xc - cm*Xo) - ((1+cm)Uc - cm*Uo)
//          (y/Xc/Xo/Uc/Uo are 4 MB each -> L2/L3-resident; no res buffer).
// Phase 2: conv -> acc[4][4] (weights in SGPRs).
// Phase 3: acc -> LDS flat [16][250] (overlays lres after sync).
// Phase 4: streaming float4 epilogue (proven v5): s_next = mom(s_cur,s_old)
//          + acc*INVL, soft-threshold for u-fields.
// ---------------------------------------------------------------------------
__global__ __launch_bounds__(256) void k_update(
    const float* __restrict__ yimg,
    const float* __restrict__ Xc, const float* __restrict__ Xo,
    const float* __restrict__ Uc, const float* __restrict__ Uo,
    const float* sx_cur, const float* sx_old,
    const float* su_cur, const float* su_old,
    float* sx_next, float* su_next,
    const float* __restrict__ Afil, const float* __restrict__ Bfil,
    float cmom, int first)
{
    __shared__ float smem[22*LRS + 8];       // lres; later overlaid by acc flat

    const int c   = blockIdx.x;              // 0..63 (0-31: x/A, 32-63: u/B)
    const int p0  = blockIdx.y * 16;
    const int n   = blockIdx.z;
    const int tid = threadIdx.x;
    const bool isx = (c < CC);
    const int  cf  = isx ? c : c - CC;

    const bool momentum = (!first) && (cmom != 0.0f);
    const bool plain    = (!first) && (cmom == 0.0f);
    const float cp = 1.0f + cmom;

    // ---- phase 1: stage res tile (computed from images) ----
    const size_t ib = (size_t)n * IMG_SZ;
#pragma unroll
    for (int it = 0; it < 6; ++it) {
        int idx = tid + it*256;
        if (idx < 22*64) {
            int r = idx >> 6, c4 = (idx & 63) << 2;
            int gr = p0 + r;
            float4 rv = make_float4(0.f,0.f,0.f,0.f);
            if (gr < HH) {
                size_t o = ib + (size_t)gr*WW + c4;
                float4 yv = *(const float4*)(yimg + o);
                if (first) {
                    rv = yv;
                } else if (momentum) {
                    float4 xc = *(const float4*)(Xc + o);
                    float4 xo = *(const float4*)(Xo + o);
                    float4 uc = *(const float4*)(Uc + o);
                    float4 uo = *(const float4*)(Uo + o);
                    rv.x = yv.x - ALPHA*(cp*xc.x - cmom*xo.x) - (cp*uc.x - cmom*uo.x);
                    rv.y = yv.y - ALPHA*(cp*xc.y - cmom*xo.y) - (cp*uc.y - cmom*uo.y);
                    rv.z = yv.z - ALPHA*(cp*xc.z - cmom*xo.z) - (cp*uc.z - cmom*uo.z);
                    rv.w = yv.w - ALPHA*(cp*xc.w - cmom*xo.w) - (cp*uc.w - cmom*uo.w);
                } else {                      // cm==0: don't touch old images
                    float4 xc = *(const float4*)(Xc + o);
                    float4 uc = *(const float4*)(Uc + o);
                    rv.x = yv.x - ALPHA*xc.x - uc.x;
                    rv.y = yv.y - ALPHA*xc.y - uc.y;
                    rv.z = yv.z - ALPHA*xc.z - uc.z;
                    rv.w = yv.w - ALPHA*xc.w - uc.w;
                }
            }
            *(float4*)&smem[r*LRS + c4] = rv;
        }
    }
    if (tid < 8) smem[22*LRS + tid] = 0.f;

    const float* Wp = (isx ? Afil : Bfil) + cf*49;
    float wt[7][7];
#pragma unroll
    for (int a = 0; a < 7; ++a)
#pragma unroll
        for (int b = 0; b < 7; ++b)
            wt[a][b] = rfl(Wp[a*7 + b]);

    __syncthreads();

    // ---- phase 2: conv ----
    const int tq = tid & 63;
    const int pg = tid >> 6;
    const int q4 = tq << 2;

    float acc[4][4];
#pragma unroll
    for (int k = 0; k < 4; ++k)
#pragma unroll
        for (int j = 0; j < 4; ++j) acc[k][j] = 0.f;

#pragma unroll
    for (int rr = 0; rr < 10; ++rr) {
        const float4* lp = (const float4*)&smem[(pg*4 + rr)*LRS + q4];
        float4 A0 = lp[0], A1 = lp[1], A2 = lp[2];
        float win[12] = {A0.x,A0.y,A0.z,A0.w, A1.x,A1.y,A1.z,A1.w,
                         A2.x,A2.y,A2.z,A2.w};
#pragma unroll
        for (int k = 0; k < 4; ++k) {
            const int a = rr - k;
            if (a >= 0 && a < 7) {
#pragma unroll
                for (int b = 0; b < 7; ++b) {
                    float wv = wt[a][b];
#pragma unroll
                    for (int j = 0; j < 4; ++j)
                        acc[k][j] += win[b + j] * wv;
                }
            }
        }
    }

    __syncthreads();   // all lres reads done; safe to overlay

    // ---- phase 3: acc -> LDS flat [16][250] ----
#pragma unroll
    for (int k = 0; k < 4; ++k) {
        int p = p0 + pg*4 + k;
        if (p < DD) {
            int lr = pg*4 + k;
            if (q4 <= 244)
                *(float4*)&smem[lr*250 + q4] =
                    make_float4(acc[k][0], acc[k][1], acc[k][2], acc[k][3]);
            else if (q4 == 248)
                *(float2*)&smem[lr*250 + q4] =
                    make_float2(acc[k][0], acc[k][1]);
        }
    }
    __syncthreads();

    // ---- phase 4: streaming epilogue ----
    const int rows = (DD - p0 < 16) ? (DD - p0) : 16;   // 16 or 10
    const int nf4  = (rows * 250) >> 2;
    const size_t gb = ((size_t)n*CC + cf) * FLD_SZ + (size_t)p0 * DD;

    const float* scur  = (isx ? sx_cur  : su_cur)  + gb;
    const float* sold  = (isx ? sx_old  : su_old)  + gb;
    float*       snext = (isx ? sx_next : su_next) + gb;

    float4 av[4], scv[4], sov[4];
    bool ok[4];
#pragma unroll
    for (int j = 0; j < 4; ++j) {
        int i4 = tid + j*256;
        ok[j] = (i4 < nf4);
        if (ok[j]) {
            av[j] = *(const float4*)&smem[i4 << 2];
            if (momentum) {
                scv[j] = *(const float4*)(scur + (i4 << 2));
                sov[j] = *(const float4*)(sold + (i4 << 2));
            } else if (plain) {
                scv[j] = *(const float4*)(scur + (i4 << 2));
            }
        }
    }
#pragma unroll
    for (int j = 0; j < 4; ++j) {
        if (ok[j]) {
            float4 o;
            if (momentum) {
                o.x = scv[j].x + cmom*(scv[j].x - sov[j].x) + av[j].x*INVL;
                o.y = scv[j].y + cmom*(scv[j].y - sov[j].y) + av[j].y*INVL;
                o.z = scv[j].z + cmom*(scv[j].z - sov[j].z) + av[j].z*INVL;
                o.w = scv[j].w + cmom*(scv[j].w - sov[j].w) + av[j].w*INVL;
            } else if (plain) {
                o.x = scv[j].x + av[j].x*INVL;
                o.y = scv[j].y + av[j].y*INVL;
                o.z = scv[j].z + av[j].z*INVL;
                o.w = scv[j].w + av[j].w*INVL;
            } else {
                o.x = av[j].x*INVL; o.y = av[j].y*INVL;
                o.z = av[j].z*INVL; o.w = av[j].w*INVL;
            }
            if (!isx) {
                o.x = sthr(o.x); o.y = sthr(o.y);
                o.z = sthr(o.z); o.w = sthr(o.w);
            }
            *(float4*)(snext + (tid + j*256)*4) = o;
        }
    }
}

// ---------------------------------------------------------------------------
// k_convT v6: full images directly (no partials). grid = (16, 2, 16).
// 32-channel loop with DOUBLE-BUFFERED staging: stage(c+1) issued before
// compute(c), one barrier per channel -> HBM latency hides under compute.
// Zero-padded 22x264 LDS planes; weights in SGPRs; 4x4 outputs/thread.
// ---------------------------------------------------------------------------
__global__ __launch_bounds__(256) void k_convT(
    const float* __restrict__ sx, const float* __restrict__ su,
    float* __restrict__ Xout, float* __restrict__ Uout,
    const float* __restrict__ Afil, const float* __restrict__ Bfil)
{
    __shared__ float st[2][22*264];

    const int h0  = blockIdx.x * 16;
    const int f   = blockIdx.y;
    const int n   = blockIdx.z;
    const int tid = threadIdx.x;

    const float* Sn = (f ? su : sx) + (size_t)n*CC*FLD_SZ;
    const float* Wb = f ? Bfil : Afil;
    float* O = (f ? Uout : Xout) + (size_t)n * IMG_SZ;

    // permanent zero borders in BOTH buffers (never overwritten by staging)
    for (int i = tid; i < 22*14; i += 256) {
        int r = i / 14, j = i - r*14;
        int col = (j < 6) ? j : (250 + j);
        st[0][r*264 + col] = 0.f;
        st[1][r*264 + col] = 0.f;
    }

    const int tw = tid & 63;
    const int hg = tid >> 6;
    const int w4 = tw << 2;

    float acc[4][4];
#pragma unroll
    for (int k = 0; k < 4; ++k)
#pragma unroll
        for (int j = 0; j < 4; ++j) acc[k][j] = 0.f;

    // prologue: stage channel 0 into buf 0
    {
        const float* Sp = Sn;
        for (int i = tid; i < 22*125; i += 256) {
            int r = i / 125, j = i - r*125;
            int sr = h0 - 6 + r;
            float2 v = make_float2(0.f, 0.f);
            if (sr >= 0 && sr < DD) v = *(const float2*)(Sp + (size_t)sr*DD + 2*j);
            *(float2*)&st[0][r*264 + 6 + 2*j] = v;
        }
    }

    for (int c = 0; c < CC; ++c) {
        const int buf = c & 1;
        __syncthreads();                     // staging of buf done; buf^1 free
        if (c + 1 < CC) {                    // issue next-channel staging first
            const float* Sp = Sn + (size_t)(c+1) * FLD_SZ;
            for (int i = tid; i < 22*125; i += 256) {
                int r = i / 125, j = i - r*125;
                int sr = h0 - 6 + r;
                float2 v = make_float2(0.f, 0.f);
                if (sr >= 0 && sr < DD) v = *(const float2*)(Sp + (size_t)sr*DD + 2*j);
                *(float2*)&st[buf^1][r*264 + 6 + 2*j] = v;
            }
        }
        float wt[7][7];
#pragma unroll
        for (int a = 0; a < 7; ++a)
#pragma unroll
            for (int b = 0; b < 7; ++b)
                wt[a][b] = rfl(Wb[c*49 + a*7 + b]);

#pragma unroll
        for (int rr = 0; rr < 10; ++rr) {
            const float4* lp = (const float4*)&st[buf][(hg*4 + rr)*264 + w4];
            float4 A0 = lp[0], A1 = lp[1], A2 = lp[2];
            float win[12] = {A0.x,A0.y,A0.z,A0.w, A1.x,A1.y,A1.z,A1.w,
                             A2.x,A2.y,A2.z,A2.w};
#pragma unroll
            for (int k = 0; k < 4; ++k) {
                const int a = k + 6 - rr;
                if (a >= 0 && a < 7) {
#pragma unroll
                    for (int b = 0; b < 7; ++b) {
                        float wv = wt[a][b];
#pragma unroll
                        for (int j = 0; j < 4; ++j)
                            acc[k][j] += win[j - b + 6] * wv;
                    }
                }
            }
        }
    }

#pragma unroll
    for (int k = 0; k < 4; ++k) {
        int h = h0 + hg*4 + k;
        *(float4*)(O + (size_t)h*WW + w4) =
            make_float4(acc[k][0], acc[k][1], acc[k][2], acc[k][3]);
    }
}

// ---------------------------------------------------------------------------
// k_final: yhat = axh + buh (axh/buh already hold Ax_hat/Bu_hat in place).
// ---------------------------------------------------------------------------
__global__ __launch_bounds__(256) void k_final(
    const float* __restrict__ axh, const float* __restrict__ buh,
    float* __restrict__ yhat)
{
    int i = blockIdx.x*256 + threadIdx.x;
    if (i < IMG_TOT/4) {
        float4 x = ((const float4*)axh)[i];
        float4 u = ((const float4*)buh)[i];
        float4 s;
        s.x = x.x + u.x; s.y = x.y + u.y; s.z = x.z + u.z; s.w = x.w + u.w;
        ((float4*)yhat)[i] = s;
    }
}

extern "C" void kernel_launch(void* const* d_in, const int* in_sizes, int n_in,
                              void* d_out, int out_size, void* d_ws, size_t ws_size,
                              hipStream_t stream) {
    const float* y = (const float*)d_in[0];
    const float* A = (const float*)d_in[1];
    const float* B = (const float*)d_in[2];

    float* out  = (float*)d_out;
    float* yhat = out;                          // [IMG_TOT]
    float* xout = out + IMG_TOT;                // [FLD_TOT]
    float* uout = xout + FLD_TOT;               // [FLD_TOT]
    float* axh  = uout + FLD_TOT;               // [IMG_TOT]
    float* buh  = axh + IMG_TOT;                // [IMG_TOT]

    float* ws   = (float*)d_ws;                 // needs 2*FLD_TOT + 2*IMG_TOT
    float* Px0  = ws;                           // [FLD_TOT]
    float* Pu0  = Px0 + FLD_TOT;                // [FLD_TOT]
    float* Xi0  = Pu0 + FLD_TOT;                // [IMG_TOT]
    float* Ui0  = Xi0 + IMG_TOT;                // [IMG_TOT]

    // Parity: s_t in P[t&1]; s_15 (odd) lands in d_out slots = P[1].
    // Images of s_t in Xi[t&1]; gen-15 (parity 1) lands in axh/buh so
    // Ax_hat/Bu_hat are produced in place; k_final only sums them.
    float* Px[2] = {Px0, xout};
    float* Pu[2] = {Pu0, uout};
    float* Xi[2] = {Xi0, axh};
    float* Ui[2] = {Ui0, buh};

    // FISTA momentum coefficients; step t uses cv[t-1]; cv[0] == 0 exactly.
    float cv[15];
    {
        float t = 1.0f;
        for (int k = 0; k < 15; ++k) {
            float tn = (1.0f + sqrtf(1.0f + 4.0f*t*t)) * 0.5f;
            cv[k] = (t - 1.0f) / tn;
            t = tn;
        }
    }

    dim3 blk(256);
    dim3 gU(64, 16, NB);                        // (channel, p-tile, n)
    dim3 gT(16, 2, NB);                         // (h-tile, field, n)
    int  gE = (IMG_TOT/4 + 255)/256;

    // step 0: res == y, tmp == 0; writes s_1 into P[1]
    k_update<<<gU, blk, 0, stream>>>(y, Xi[0], Xi[0], Ui[0], Ui[0],
                                     Px[0], Px[0], Pu[0], Pu[0],
                                     Px[1], Pu[1], A, B, 0.0f, 1);
    k_convT<<<gT, blk, 0, stream>>>(Px[1], Pu[1], Xi[1], Ui[1], A, B);

    for (int t = 1; t < 15; ++t) {
        int cur = t & 1, nxt = cur ^ 1;
        float cm = cv[t-1];
        k_update<<<gU, blk, 0, stream>>>(y, Xi[cur], Xi[nxt], Ui[cur], Ui[nxt],
                                         Px[cur], Px[nxt], Pu[cur], Pu[nxt],
                                         Px[nxt], Pu[nxt], A, B, cm, 0);
        k_convT<<<gT, blk, 0, stream>>>(Px[nxt], Pu[nxt], Xi[nxt], Ui[nxt], A, B);
    }

    k_final<<<gE, blk, 0, stream>>>(axh, buh, yhat);
}

// Round 8
// 4218.040 us; speedup vs baseline: 1.9234x; 1.9234x over previous
//
#include <hip/hip_runtime.h>
#include <cmath>

// ---- problem constants ----
#define NB 16
#define CC 32          // channels per dictionary (A and B each)
#define HH 256
#define WW 256
#define DD 250         // 256 - 7 + 1
#define ALPHA 2.0f     // 1 + 1/RHO
#define INVL 0.1f      // 1/L
#define THR 0.01f      // LAM/L

#define IMG_SZ (HH*WW)                       // 65536
#define IMG_TOT (NB*IMG_SZ)                  // 1,048,576
#define FLD_SZ (DD*DD)                       // 62,500
#define FLD_TOT ((size_t)NB*CC*FLD_SZ)       // 32,000,000

#define SRS 264                              // LDS row stride (floats)

// block-uniform float -> SGPR (filter taps become the s-operand of v_fma)
__device__ __forceinline__ float rfl(float x) {
    return __int_as_float(__builtin_amdgcn_readfirstlane(__float_as_int(x)));
}
__device__ __forceinline__ float sthr(float v) {
    float a = fabsf(v) - THR; a = a > 0.f ? a : 0.f;
    return (v > 0.f) ? a : ((v < 0.f) ? -a : 0.f);
}

// conv: out[e][j] += wt[a][b] * res[row][q4 + b + j]   (win = res cols q4..q4+11)
#define CONV_ROW(ACC, Aa) do { \
    _Pragma("unroll") \
    for (int b = 0; b < 7; ++b) { \
        const float wv = wt[Aa][b]; \
        ACC.x += wv*win[b+0]; ACC.y += wv*win[b+1]; \
        ACC.z += wv*win[b+2]; ACC.w += wv*win[b+3]; \
    } } while (0)

// gather (convT): img[d][j] += wt[a][b] * s[k][w4 + j - b]
// win = stile cols (cs) w4..w4+11 where cs = scol + 8 -> idx = 8 + j - b
#define GATH_ROW(ACC, Aa) do { \
    _Pragma("unroll") \
    for (int b = 0; b < 7; ++b) { \
        const float wv = wt[Aa][b]; \
        ACC.x += wv*win[8-b+0]; ACC.y += wv*win[8-b+1]; \
        ACC.z += wv*win[8-b+2]; ACC.w += wv*win[8-b+3]; \
    } } while (0)

// ---------------------------------------------------------------------------
// k_step: FUSED update + convT. Block = (p-tile of 16 rows, field, n),
// 512 threads, all 32 channels.
// Per channel c:
//   conv(res_tile, W_c) -> s_next (2 rows x 4 cols / thread)  [weights->SGPR]
//   s_next -> global field AND double-buffered LDS s-tile
//   gather: img_acc(regs, 3 rows x 4 cols / thread) += convT(s_tile, W_c)
// End: img rows [6,15] (exclusive owner) plain-stored; boundary rows [0,5],
// [16,21] atomicAdd into the zeroed image accumulators.
// ---------------------------------------------------------------------------
__global__ __launch_bounds__(512) void k_step(
    const float* __restrict__ rin,          // res image (or y at step 0)
    const float* sx_cur, const float* su_cur,
    float* sx_on, float* su_on,             // s_old == s_next (read then write)
    float* __restrict__ Ximg, float* __restrict__ Uimg,  // accumulated convT images
    const float* __restrict__ Afil, const float* __restrict__ Bfil,
    float cmom, int first)
{
    __shared__ __align__(16) float resT[22*SRS];
    __shared__ __align__(16) float stile[2][16*SRS];

    const int p0  = blockIdx.x * 16;
    const int f   = blockIdx.y;
    const int n   = blockIdx.z;
    const int tid = threadIdx.x;
    const bool isx = (f == 0);

    // zero both s-tile buffers (borders + beyond-DD rows rely on this)
    {
        float4 z = make_float4(0.f,0.f,0.f,0.f);
        float4* sp = (float4*)&stile[0][0];
        for (int i = tid; i < 2*16*SRS/4; i += 512) sp[i] = z;
    }
    // stage res tile rows [p0 .. p0+21], cols 0..255 (+8 zero cols pad)
    {
        const float* rb = rin + (size_t)n * IMG_SZ;
        for (int i = tid; i < 22*66; i += 512) {
            int r  = i / 66;
            int c4 = (i - r*66) << 2;
            int gr = p0 + r;
            float4 v = make_float4(0.f,0.f,0.f,0.f);
            if (gr < HH && c4 < WW) v = *(const float4*)(rb + gr*WW + c4);
            *(float4*)&resT[r*SRS + c4] = v;
        }
    }
    __syncthreads();

    const int rg  = tid >> 6;               // 0..7 (wave-uniform)
    const int q4  = (tid & 63) << 2;        // 0..252
    const bool qok = (q4 <= 248);           // q4==252 lanes idle for conv/state
    const int p_0 = p0 + 2*rg;              // conv output rows p_0, p_0+1

    const float* Wb   = isx ? Afil : Bfil;
    const float* scur = isx ? sx_cur : su_cur;
    float*       sON  = isx ? sx_on  : su_on;    // old AND next
    float*       img  = (isx ? Ximg : Uimg) + (size_t)n * IMG_SZ;

    const bool momentum = (!first) && (cmom != 0.f);
    const bool plain    = (!first) && (cmom == 0.f);

    float4 ia0 = make_float4(0.f,0.f,0.f,0.f), ia1 = ia0, ia2 = ia0;

    const size_t fbase = (size_t)n * CC * FLD_SZ;
    const bool r0ok = qok && (p_0     < DD);
    const bool r1ok = qok && (p_0 + 1 < DD);
    const size_t off0 = fbase + (size_t)p_0*DD + q4;       // + c*FLD_SZ
    const size_t off1 = off0 + DD;

    for (int c = 0; c < CC; ++c) {
        // filter taps -> SGPRs
        float wt[7][7];
        {
            const float* Wp = Wb + c*49;
#pragma unroll
            for (int a = 0; a < 7; ++a)
#pragma unroll
                for (int b = 0; b < 7; ++b)
                    wt[a][b] = rfl(Wp[a*7 + b]);
        }

        // state loads early (float4 reads may overhang 2 floats into the
        // adjacent buffer at q4==248 -- memory-safe by layout; .zw unused)
        const size_t co = (size_t)c * FLD_SZ;
        float4 sc0 = make_float4(0.f,0.f,0.f,0.f), sc1 = sc0, so0 = sc0, so1 = sc0;
        if (momentum) {
            if (r0ok) { sc0 = *(const float4*)(scur + co + off0);
                        so0 = *(const float4*)(sON  + co + off0); }
            if (r1ok) { sc1 = *(const float4*)(scur + co + off1);
                        so1 = *(const float4*)(sON  + co + off1); }
        } else if (plain) {
            if (r0ok) sc0 = *(const float4*)(scur + co + off0);
            if (r1ok) sc1 = *(const float4*)(scur + co + off1);
        }

        // conv: rows p_0, p_0+1 from res rows (2rg .. 2rg+7)
        float4 a0 = make_float4(0.f,0.f,0.f,0.f), a1 = a0;
#pragma unroll
        for (int rr = 0; rr < 8; ++rr) {
            const float* lp = &resT[(2*rg + rr)*SRS + q4];
            float4 A0 = *(const float4*)lp;
            float4 A1 = *(const float4*)(lp + 4);
            float4 A2 = *(const float4*)(lp + 8);
            const float win[12] = {A0.x,A0.y,A0.z,A0.w, A1.x,A1.y,A1.z,A1.w,
                                   A2.x,A2.y,A2.z,A2.w};
            if (rr <= 6) CONV_ROW(a0, rr);       // e=0: a = rr
            if (rr >= 1) CONV_ROW(a1, rr-1);     // e=1: a = rr-1
        }

        // epilogue: s_next values
        float4 o0 = make_float4(a0.x*INVL, a0.y*INVL, a0.z*INVL, a0.w*INVL);
        float4 o1 = make_float4(a1.x*INVL, a1.y*INVL, a1.z*INVL, a1.w*INVL);
        if (momentum) {
            o0.x += sc0.x + cmom*(sc0.x - so0.x);
            o0.y += sc0.y + cmom*(sc0.y - so0.y);
            o0.z += sc0.z + cmom*(sc0.z - so0.z);
            o0.w += sc0.w + cmom*(sc0.w - so0.w);
            o1.x += sc1.x + cmom*(sc1.x - so1.x);
            o1.y += sc1.y + cmom*(sc1.y - so1.y);
            o1.z += sc1.z + cmom*(sc1.z - so1.z);
            o1.w += sc1.w + cmom*(sc1.w - so1.w);
        } else if (plain) {
            o0.x += sc0.x; o0.y += sc0.y; o0.z += sc0.z; o0.w += sc0.w;
            o1.x += sc1.x; o1.y += sc1.y; o1.z += sc1.z; o1.w += sc1.w;
        }
        if (!isx) {
            o0.x = sthr(o0.x); o0.y = sthr(o0.y); o0.z = sthr(o0.z); o0.w = sthr(o0.w);
            o1.x = sthr(o1.x); o1.y = sthr(o1.y); o1.z = sthr(o1.z); o1.w = sthr(o1.w);
        }

        // global store of s_next
        if (r0ok) {
            float* dst = sON + co + off0;
            if (q4 <= 244) *(float4*)dst = o0;
            else           *(float2*)dst = make_float2(o0.x, o0.y);
        }
        if (r1ok) {
            float* dst = sON + co + off1;
            if (q4 <= 244) *(float4*)dst = o1;
            else           *(float2*)dst = make_float2(o1.x, o1.y);
        }

        // s-tile write (1 barrier/channel: gather(c-2) on this buffer is
        // separated by the barriers of iterations c-2 and c-1)
        const int bb = c & 1;
        if (r0ok) {
            float* d0 = &stile[bb][(2*rg)*SRS + q4 + 8];
            if (q4 <= 244) *(float4*)d0 = o0;
            else           *(float2*)d0 = make_float2(o0.x, o0.y);
        }
        if (r1ok) {
            float* d1 = &stile[bb][(2*rg + 1)*SRS + q4 + 8];
            if (q4 <= 244) *(float4*)d1 = o1;
            else           *(float2*)d1 = make_float2(o1.x, o1.y);
        }
        __syncthreads();

        // gather: img rows 3rg..3rg+2 <- convT(stile[bb])
#pragma unroll
        for (int k9 = 0; k9 < 9; ++k9) {
            const int k = 3*rg - 6 + k9;             // s-tile row (wave-uniform)
            if (k >= 0 && k < 16) {
                const float* sp = &stile[bb][k*SRS + q4];
                float4 B0 = *(const float4*)sp;
                float4 B1 = *(const float4*)(sp + 4);
                float4 B2 = *(const float4*)(sp + 8);
                const float win[12] = {B0.x,B0.y,B0.z,B0.w, B1.x,B1.y,B1.z,B1.w,
                                       B2.x,B2.y,B2.z,B2.w};
                if (k9 <= 6)            GATH_ROW(ia0, 6 - k9);
                if (k9 >= 1 && k9 <= 7) GATH_ROW(ia1, 7 - k9);
                if (k9 >= 2)            GATH_ROW(ia2, 8 - k9);
            }
        }
    }

    // image write-out: rows h in [6,15] exclusive -> plain store;
    // boundary rows -> atomicAdd (buffers pre-zeroed by k_res / k_zero)
#pragma unroll
    for (int d = 0; d < 3; ++d) {
        const int h = 3*rg + d;
        if (h < 22) {
            const int habs = p0 + h;
            if (habs < HH) {
                float4 v = (d == 0) ? ia0 : (d == 1) ? ia1 : ia2;
                float* ip = img + (size_t)habs*WW + q4;
                if (h >= 6 && h <= 15) {
                    *(float4*)ip = v;
                } else {
                    atomicAdd(ip + 0, v.x);
                    atomicAdd(ip + 1, v.y);
                    atomicAdd(ip + 2, v.z);
                    atomicAdd(ip + 3, v.w);
                }
            }
        }
    }
}

// ---------------------------------------------------------------------------
// k_res: res = y - ALPHA*((1+cm)X - cm*Xprev) - ((1+cm)U - cm*Uprev);
// save combined X,U for next gen; re-zero the accumulators. All L3-hot.
// ---------------------------------------------------------------------------
__global__ __launch_bounds__(256) void k_res(
    const float* __restrict__ y,
    float* Xp, float* Up,                   // accumulated images (read then zero)
    float* Xc, float* Uc,                   // prev combined (read if cm!=0, then overwrite)
    float* __restrict__ resb, float cm)
{
    int i = blockIdx.x*256 + threadIdx.x;
    if (i >= IMG_TOT/4) return;
    float4 xc = ((const float4*)Xp)[i];
    float4 uc = ((const float4*)Up)[i];
    float4 xo = make_float4(0.f,0.f,0.f,0.f), uo = xo;
    if (cm != 0.f) {
        xo = ((const float4*)Xc)[i];
        uo = ((const float4*)Uc)[i];
    }
    ((float4*)Xc)[i] = xc;
    ((float4*)Uc)[i] = uc;
    float4 z = make_float4(0.f,0.f,0.f,0.f);
    ((float4*)Xp)[i] = z;
    ((float4*)Up)[i] = z;
    float4 yv = ((const float4*)y)[i];
    const float cp = 1.f + cm;
    float4 r;
    r.x = yv.x - ALPHA*(cp*xc.x - cm*xo.x) - (cp*uc.x - cm*uo.x);
    r.y = yv.y - ALPHA*(cp*xc.y - cm*xo.y) - (cp*uc.y - cm*uo.y);
    r.z = yv.z - ALPHA*(cp*xc.z - cm*xo.z) - (cp*uc.z - cm*uo.z);
    r.w = yv.w - ALPHA*(cp*xc.w - cm*xo.w) - (cp*uc.w - cm*uo.w);
    ((float4*)resb)[i] = r;
}

__global__ __launch_bounds__(256) void k_zero2(float* a, float* b)
{
    int i = blockIdx.x*256 + threadIdx.x;
    if (i < IMG_TOT/4) {
        float4 z = make_float4(0.f,0.f,0.f,0.f);
        ((float4*)a)[i] = z;
        ((float4*)b)[i] = z;
    }
}

// k_final: yhat = axh + buh (axh/buh already hold Ax_hat / Bu_hat)
__global__ __launch_bounds__(256) void k_final(
    const float* __restrict__ axh, const float* __restrict__ buh,
    float* __restrict__ yhat)
{
    int i = blockIdx.x*256 + threadIdx.x;
    if (i < IMG_TOT/4) {
        float4 x = ((const float4*)axh)[i];
        float4 u = ((const float4*)buh)[i];
        float4 s;
        s.x = x.x + u.x; s.y = x.y + u.y; s.z = x.z + u.z; s.w = x.w + u.w;
        ((float4*)yhat)[i] = s;
    }
}

extern "C" void kernel_launch(void* const* d_in, const int* in_sizes, int n_in,
                              void* d_out, int out_size, void* d_ws, size_t ws_size,
                              hipStream_t stream) {
    const float* y = (const float*)d_in[0];
    const float* A = (const float*)d_in[1];
    const float* B = (const float*)d_in[2];

    float* out  = (float*)d_out;
    float* yhat = out;                          // [IMG_TOT]
    float* xout = out + IMG_TOT;                // [FLD_TOT]  s_15 x
    float* uout = xout + FLD_TOT;               // [FLD_TOT]  s_15 u
    float* axh  = uout + FLD_TOT;               // [IMG_TOT]  X accumulator / Ax_hat
    float* buh  = axh + IMG_TOT;                // [IMG_TOT]  U accumulator / Bu_hat

    float* ws   = (float*)d_ws;                 // needs 2*FLD_TOT + 2*IMG_TOT (264 MB)
    float* Px0  = ws;                           // [FLD_TOT]
    float* Pu0  = Px0 + FLD_TOT;                // [FLD_TOT]
    float* Xc   = Pu0 + FLD_TOT;                // [IMG_TOT]  combined X (prev gen)
    float* Uc   = Xc + IMG_TOT;                 // [IMG_TOT]  combined U (prev gen)

    // State ping-pong. k_step(t) reads s_t from P[t&1], writes s_{t+1} into
    // P[(t+1)&1] (which also holds s_{t-1} = the momentum "old" - exact-offset
    // read-then-write per thread). t=14 writes into P[1] = d_out slots.
    float* Px[2] = {Px0, xout};
    float* Pu[2] = {Pu0, uout};
    float* res   = yhat;                        // borrowed; rewritten by k_final

    // FISTA momentum coefficients; step t (>=1) uses cv[t-1]; cv[0]==0.
    float cv[15];
    {
        float t = 1.0f;
        for (int k = 0; k < 15; ++k) {
            float tn = (1.0f + sqrtf(1.0f + 4.0f*t*t)) * 0.5f;
            cv[k] = (t - 1.0f) / tn;
            t = tn;
        }
    }

    dim3 blk512(512), blk256(256);
    dim3 gS(16, 2, NB);                         // (p-tile, field, n)
    int  gE = (IMG_TOT/4 + 255)/256;

    k_zero2<<<gE, blk256, 0, stream>>>(axh, buh);

    // t = 0: res == y, no state reads; writes s_1 + accumulates gen-1 images
    k_step<<<gS, blk512, 0, stream>>>(y, Px[0], Pu[0], Px[1], Pu[1],
                                      axh, buh, A, B, 0.0f, 1);

    for (int t = 1; t < 15; ++t) {
        float cm = cv[t-1];
        k_res<<<gE, blk256, 0, stream>>>(y, axh, buh, Xc, Uc, res, cm);
        k_step<<<gS, blk512, 0, stream>>>(res, Px[t&1], Pu[t&1],
                                          Px[(t+1)&1], Pu[(t+1)&1],
                                          axh, buh, A, B, cm, 0);
    }

    k_final<<<gE, blk256, 0, stream>>>(axh, buh, yhat);
}